// Round 8
// baseline (301.482 us; speedup 1.0000x reference)
//
#include <hip/hip_runtime.h>

#define BATCH 16384
#define LSEQ  50
#define DIN   20
#define CHN   16
#define HID   6

__device__ __forceinline__ float frcp(float x){ return __builtin_amdgcn_rcpf(x); }
__device__ __forceinline__ float fsig(float x){ return frcp(1.0f + __expf(-x)); }
__device__ __forceinline__ float ftanh(float x){ float t = __expf(2.0f*x); return (t - 1.0f) * frcp(t + 1.0f); }
__device__ __forceinline__ float lrelu(float v){ return v > 0.0f ? v : 0.1f*v; }

// Per-wave LDS slab = 2048 floats (8192 B) -> 32768 B/block -> 5 blocks/CU (20 waves).
//  [0,840)     sXEp: padded conv rows, stride 52: P[i][2+m] = xe_flat[i*50+m]; shared pads.
//              After conv: sY aliases [0,300).
//  [840,1740)  R1  : gi rows [50][18] -> sAT [50][16] -> sC [50][16] {T[0..5],-,WX[8..13]}
//              sFE = R1+800 -> [1640,1694) (dead gi tail; disjoint from sAT/sC)
//  [1740,2040) sX4 : x4 flat (l*6+h)
constexpr int SLAB = 2048;

__global__ __launch_bounds__(256, 5) void fused_kernel(
    const float* __restrict__ x,
    const float* __restrict__ we_w, const float* __restrict__ we_b,
    const float* __restrict__ attn_w, const float* __restrict__ attn_b,
    const float* __restrict__ c1w, const float* __restrict__ c1b,
    const float* __restrict__ c2w, const float* __restrict__ c2b,
    const float* __restrict__ c3w, const float* __restrict__ c3b,
    const float* __restrict__ wih, const float* __restrict__ whh,
    const float* __restrict__ bih, const float* __restrict__ bhh,
    const float* __restrict__ fc3w, const float* __restrict__ fc3b,
    float* __restrict__ out)
{
  __shared__ __align__(16) float smem[4 * SLAB];
  const int tid  = threadIdx.x;
  const int wave = tid >> 6;
  const int lane = tid & 63;
  const int b    = blockIdx.x * 4 + wave;

  float* S    = smem + wave * SLAB;
  float* sXEp = S;
  float* sY   = S;          // alias, live after conv
  float* R1   = S + 840;
  float* sFE  = S + 1640;   // R1+800
  float* sX4  = S + 1740;

  const float* xb = x + (size_t)b * (LSEQ * DIN);

  // ---- zero the shared row pads ----
  if (lane < CHN) {
    sXEp[lane * 52]     = 0.0f;
    sXEp[lane * 52 + 1] = 0.0f;
  } else if (lane == 16) {
    sXEp[832] = 0.0f;
    sXEp[833] = 0.0f;
  }

  // ---- Phase 1+3: lane l computes xe[l][0..15] (scatter to padded rows) and gi[l][0..17] ----
  if (lane < LSEQ) {
    float xv[DIN];
    const float4* xr = (const float4*)(xb + lane * DIN);
    #pragma unroll
    for (int q = 0; q < 5; ++q) {
      float4 v = xr[q];
      xv[4*q] = v.x; xv[4*q+1] = v.y; xv[4*q+2] = v.z; xv[4*q+3] = v.w;
    }
    float xe[CHN];
    #pragma unroll
    for (int c = 0; c < CHN; ++c) {
      float a = we_b[c];
      #pragma unroll
      for (int d = 0; d < DIN; ++d) a = fmaf(xv[d], we_w[c * DIN + d], a);
      xe[c] = a;
    }
    // scatter: kk = 16*lane + c ; i = kk/50, m = kk%50 ; addr = 52i + 2 + m
    const int kk0 = lane * CHN;
    const int i0  = kk0 / 50;
    const int m0  = kk0 - i0 * 50;
    float* basep = sXEp + i0 * 52 + 2 + m0;
    #pragma unroll
    for (int c = 0; c < CHN; ++c) {
      const int off = c + ((m0 + c >= 50) ? 2 : 0);
      basep[off] = xe[c];
    }
    float gi[18];
    #pragma unroll
    for (int g = 0; g < 18; ++g) {
      float a = bih[g];
      #pragma unroll
      for (int cc = 0; cc < CHN; ++cc) a = fmaf(xe[cc], wih[g * CHN + cc], a);
      gi[g] = a;
    }
    float* gd = R1 + lane * 18;
    #pragma unroll
    for (int k = 0; k < 9; ++k)
      *(float2*)(gd + 2 * k) = make_float2(gi[2 * k], gi[2 * k + 1]);
  }
  __syncthreads();

  // ---- Phase 4: GRU — wave 0 runs all 4 elements, 16 lanes each ----
  if (wave == 0) {
    const int q = lane >> 4;
    const int g = lane & 15;
    const int gb = 16 + (g & 1);
    float wa[HID], wb[HID];
    #pragma unroll
    for (int k = 0; k < HID; ++k) { wa[k] = whh[g * HID + k]; wb[k] = whh[gb * HID + k]; }
    const float ba = bhh[g];
    const float bb = bhh[gb];

    float* giq = smem + q * SLAB + 840;    // gi rows [l][18]
    float* x4q = smem + q * SLAB + 1740;

    const int base = q << 4;
    const int srcZ = base + 6 + g;
    const int srcN = base + ((g < 4) ? (12 + g) : (g - 4));

    float hh[HID];
    #pragma unroll
    for (int k = 0; k < HID; ++k) hh[k] = 0.0f;

    for (int l = 0; l < LSEQ; ++l) {
      const float gia = giq[l * 18 + g];
      const float gib = giq[l * 18 + gb];
      float gha = ba, ghb = bb;
      #pragma unroll
      for (int k = 0; k < HID; ++k) {
        gha = fmaf(wa[k], hh[k], gha);
        ghb = fmaf(wb[k], hh[k], ghb);
      }
      const float siga = fsig(gia + gha);
      const float ghx = (g >= 12) ? gha : ghb;
      const float gix = (g >= 12) ? gia : gib;
      const float ghn = __shfl(ghx, srcN);
      const float gin = __shfl(gix, srcN);
      const float z   = __shfl(siga, srcZ);
      const float n   = ftanh(fmaf(siga, ghn, gin));
      const float hn  = fmaf(z, hh[g < HID ? g : 0] - n, n);
      if (g < HID) x4q[l * HID + g] = hn;
      #pragma unroll
      for (int k = 0; k < HID; ++k) hh[k] = __shfl(hn, base + k);
    }
  }
  __syncthreads();

  // ---- Phase 2: attn rows (write sAT over dead gi) ----
  if (lane < LSEQ) {
    float a[CHN];
    #pragma unroll
    for (int cc = 0; cc < CHN; ++cc) a[cc] = sXEp[cc * 52 + 2 + lane];  // reshape view
    float o[CHN];
    #pragma unroll
    for (int c = 0; c < CHN; ++c) {
      float acc = attn_b[c];
      #pragma unroll
      for (int cc = 0; cc < CHN; ++cc) acc = fmaf(a[cc], attn_w[c * CHN + cc], acc);
      o[c] = ftanh(acc);
    }
    float4* ad = (float4*)(R1 + lane * CHN);
    ad[0] = make_float4(o[0], o[1], o[2], o[3]);
    ad[1] = make_float4(o[4], o[5], o[6], o[7]);
    ad[2] = make_float4(o[8], o[9], o[10], o[11]);
    ad[3] = make_float4(o[12], o[13], o[14], o[15]);
  }
  __syncthreads();

  // ---- Phase 5: convs (vector LDS loads, padded rows) fused with attn1 reduction ----
  {
    float* sAT = R1;
    const int o   = lane & 15;
    const int seg = lane >> 4;
    const int s   = seg * 12;
    const int NL  = (seg == 3) ? 14 : 12;
    float z1[14], z2[14], z3[14];
    #pragma unroll
    for (int u = 0; u < 14; ++u) { z1[u] = 0.0f; z2[u] = 0.0f; z3[u] = 0.0f; }
    for (int i = 0; i < CHN; ++i) {
      const float w1 = c1w[o * CHN + i];
      float w2a[3], w3a[5];
      #pragma unroll
      for (int t = 0; t < 3; ++t) w2a[t] = c2w[(o * CHN + i) * 3 + t];
      #pragma unroll
      for (int t = 0; t < 5; ++t) w3a[t] = c3w[(o * CHN + i) * 5 + t];
      const float4* wp = (const float4*)(sXEp + i * 52 + s);
      float4 q0 = wp[0], q1 = wp[1], q2 = wp[2], q3 = wp[3], q4 = wp[4];
      float xv[20] = {q0.x,q0.y,q0.z,q0.w, q1.x,q1.y,q1.z,q1.w,
                      q2.x,q2.y,q2.z,q2.w, q3.x,q3.y,q3.z,q3.w,
                      q4.x,q4.y,q4.z,q4.w};
      #pragma unroll
      for (int u = 0; u < 14; ++u) {
        z1[u] = fmaf(w1, xv[u + 2], z1[u]);
        z2[u] = fmaf(w2a[0], xv[u + 1], z2[u]);
        z2[u] = fmaf(w2a[1], xv[u + 2], z2[u]);
        z2[u] = fmaf(w2a[2], xv[u + 3], z2[u]);
        z3[u] = fmaf(w3a[0], xv[u],     z3[u]);
        z3[u] = fmaf(w3a[1], xv[u + 1], z3[u]);
        z3[u] = fmaf(w3a[2], xv[u + 2], z3[u]);
        z3[u] = fmaf(w3a[3], xv[u + 3], z3[u]);
        z3[u] = fmaf(w3a[4], xv[u + 4], z3[u]);
      }
    }
    const float b1v = c1b[o], b2v = c2b[o], b3v = c3b[o];
    float a1 = 0.0f, a2 = 0.0f, a3 = 0.0f;
    #pragma unroll
    for (int u = 0; u < 14; ++u) {
      if (u < NL) {
        int l = s + u;
        float v1 = lrelu(z1[u] + b1v);
        float v2 = lrelu(z2[u] + b2v);
        float v3 = lrelu(z3[u] + b3v);
        int f1 = o * LSEQ + l;
        int f2 = (CHN + o) * LSEQ + l;
        int f3 = (2 * CHN + o) * LSEQ + l;
        a1 += v1 * sAT[(f1 / 48) * CHN + ((f1 % 48) & 15)];
        a2 += v2 * sAT[(f2 / 48) * CHN + ((f2 % 48) & 15)];
        a3 += v3 * sAT[(f3 / 48) * CHN + ((f3 % 48) & 15)];
      }
    }
    a1 += __shfl_xor(a1, 16); a1 += __shfl_xor(a1, 32);
    a2 += __shfl_xor(a2, 16); a2 += __shfl_xor(a2, 32);
    a3 += __shfl_xor(a3, 16); a3 += __shfl_xor(a3, 32);
    if (lane < CHN) { sFE[o] = a1; sFE[CHN + o] = a2; sFE[2 * CHN + o] = a3; }
  }
  __syncthreads();

  // ---- Phase 6a: T rows + column normalizers; sC[j] = {T[0..5], -, WX[8..13]} ----
  float* sC = R1;
  if (lane < LSEQ) {
    float colj[HID];
    #pragma unroll
    for (int h = 0; h < HID; ++h) colj[h] = sX4[h * LSEQ + lane];   // flat reshape view
    *(float4*)(sC + lane * 16)     = make_float4(colj[0], colj[1], colj[2], colj[3]);
    *(float2*)(sC + lane * 16 + 4) = make_float2(colj[4], colj[5]);
    float zs = 0.0f;
    for (int i = 0; i < LSEQ; ++i) {
      const float2 r0 = *(const float2*)(sX4 + i * 6);
      const float2 r1 = *(const float2*)(sX4 + i * 6 + 2);
      const float2 r2 = *(const float2*)(sX4 + i * 6 + 4);
      float s = r0.x * colj[0];
      s = fmaf(r0.y, colj[1], s); s = fmaf(r1.x, colj[2], s);
      s = fmaf(r1.y, colj[3], s); s = fmaf(r2.x, colj[4], s);
      s = fmaf(r2.y, colj[5], s);
      zs += __expf(s * (1.0f / 6.0f));
    }
    const float zi = frcp(zs);
    const float2 q0 = *(const float2*)(sX4 + lane * 6);
    const float2 q1 = *(const float2*)(sX4 + lane * 6 + 2);
    const float2 q2 = *(const float2*)(sX4 + lane * 6 + 4);
    *(float4*)(sC + lane * 16 + 8)  = make_float4(zi*q0.x, zi*q0.y, zi*q1.x, zi*q1.y);
    *(float2*)(sC + lane * 16 + 12) = make_float2(zi*q2.x, zi*q2.y);
  }
  __syncthreads();

  // ---- Phase 6b: y0[i][h] = sum_j exp(s[i,j]/6) * WX[j][h] ----
  if (lane < LSEQ) {
    float rowi[HID];
    {
      const float2 q0 = *(const float2*)(sX4 + lane * 6);
      const float2 q1 = *(const float2*)(sX4 + lane * 6 + 2);
      const float2 q2 = *(const float2*)(sX4 + lane * 6 + 4);
      rowi[0] = q0.x; rowi[1] = q0.y; rowi[2] = q1.x;
      rowi[3] = q1.y; rowi[4] = q2.x; rowi[5] = q2.y;
    }
    float ya[HID];
    #pragma unroll
    for (int h = 0; h < HID; ++h) ya[h] = 0.0f;
    for (int j = 0; j < LSEQ; ++j) {
      const float4 t0 = *(const float4*)(sC + j * 16);
      const float2 t1 = *(const float2*)(sC + j * 16 + 4);
      float s = rowi[0] * t0.x;
      s = fmaf(rowi[1], t0.y, s); s = fmaf(rowi[2], t0.z, s);
      s = fmaf(rowi[3], t0.w, s); s = fmaf(rowi[4], t1.x, s);
      s = fmaf(rowi[5], t1.y, s);
      const float e = __expf(s * (1.0f / 6.0f));
      const float4 w0 = *(const float4*)(sC + j * 16 + 8);
      const float2 w1 = *(const float2*)(sC + j * 16 + 12);
      ya[0] = fmaf(e, w0.x, ya[0]);
      ya[1] = fmaf(e, w0.y, ya[1]);
      ya[2] = fmaf(e, w0.z, ya[2]);
      ya[3] = fmaf(e, w0.w, ya[3]);
      ya[4] = fmaf(e, w1.x, ya[4]);
      ya[5] = fmaf(e, w1.y, ya[5]);
    }
    *(float2*)(sY + lane * 6)     = make_float2(ya[0], ya[1]);
    *(float2*)(sY + lane * 6 + 2) = make_float2(ya[2], ya[3]);
    *(float2*)(sY + lane * 6 + 4) = make_float2(ya[4], ya[5]);
  }
  __syncthreads();

  // ---- Phase 7: x_gru ----
  if (lane < HID) {
    float s = 0.0f;
    for (int m = 0; m < LSEQ; ++m) s += sY[lane * LSEQ + m];
    sFE[48 + lane] = s;
  }
  __syncthreads();

  // ---- Phase 8: fc ----
  if (lane < 2) {
    float acc = fc3b[lane];
    const float* wr = fc3w + lane * 54;
    #pragma unroll
    for (int k = 0; k < 54; ++k) acc = fmaf(wr[k], sFE[k], acc);
    out[(size_t)b * 2 + lane] = acc;
  }
}

extern "C" void kernel_launch(void* const* d_in, const int* in_sizes, int n_in,
                              void* d_out, int out_size, void* d_ws, size_t ws_size,
                              hipStream_t stream) {
  (void)in_sizes; (void)n_in; (void)d_ws; (void)ws_size; (void)out_size;
  fused_kernel<<<BATCH / 4, 256, 0, stream>>>(
      (const float*)d_in[0],
      (const float*)d_in[1],  (const float*)d_in[2],
      (const float*)d_in[3],  (const float*)d_in[4],
      (const float*)d_in[5],  (const float*)d_in[6],
      (const float*)d_in[7],  (const float*)d_in[8],
      (const float*)d_in[9],  (const float*)d_in[10],
      (const float*)d_in[11], (const float*)d_in[12],
      (const float*)d_in[13], (const float*)d_in[14],
      (const float*)d_in[15], (const float*)d_in[16],
      (float*)d_out);
}

// Round 9
// 289.152 us; speedup vs baseline: 1.0426x; 1.0426x over previous
//
#include <hip/hip_runtime.h>

#define BATCH 16384
#define LSEQ  50
#define DIN   20
#define CHN   16
#define HID   6

typedef float vf2 __attribute__((ext_vector_type(2)));

__device__ __forceinline__ float frcp(float x){ return __builtin_amdgcn_rcpf(x); }
__device__ __forceinline__ float fsig(float x){ return frcp(1.0f + __expf(-x)); }
__device__ __forceinline__ float ftanh(float x){ float t = __expf(2.0f*x); return (t - 1.0f) * frcp(t + 1.0f); }
__device__ __forceinline__ float lrelu(float v){ return v > 0.0f ? v : 0.1f*v; }
__device__ __forceinline__ vf2 fma2(vf2 a, vf2 b, vf2 c){
#if __has_builtin(__builtin_elementwise_fma)
  return __builtin_elementwise_fma(a, b, c);
#else
  vf2 r; r.x = fmaf(a.x, b.x, c.x); r.y = fmaf(a.y, b.y, c.y); return r;
#endif
}

// Per-wave LDS slab (floats), SLAB = 2544 -> 40704 B/block -> 4 blocks/CU.
//  [0,840)     sXEp: padded conv rows, stride 52: P[i][2+m] = xe_flat[i*50+m]; shared pads.
//              After conv: sY aliases [0,300).
//  [840,1840)  R1  : gi rows [50][20] -> sAT [50][16] -> sC [50][16] {T[0..5],-,WX[8..13]}
//              sFE = R1+800 (dead gi tail; disjoint from sAT/sC)
//  [1840,2140) sX4 : x4 flat (l*6+h)
//  [2144,2544) sX4P: x4 padded [50][8]
constexpr int SLAB = 2544;

__global__ __launch_bounds__(256, 4) void fused_kernel(
    const float* __restrict__ x,
    const float* __restrict__ we_w, const float* __restrict__ we_b,
    const float* __restrict__ attn_w, const float* __restrict__ attn_b,
    const float* __restrict__ c1w, const float* __restrict__ c1b,
    const float* __restrict__ c2w, const float* __restrict__ c2b,
    const float* __restrict__ c3w, const float* __restrict__ c3b,
    const float* __restrict__ wih, const float* __restrict__ whh,
    const float* __restrict__ bih, const float* __restrict__ bhh,
    const float* __restrict__ fc3w, const float* __restrict__ fc3b,
    float* __restrict__ out)
{
  __shared__ __align__(16) float smem[4 * SLAB];
  const int tid  = threadIdx.x;
  const int wave = tid >> 6;
  const int lane = tid & 63;
  const int b    = blockIdx.x * 4 + wave;

  float* S    = smem + wave * SLAB;
  float* sXEp = S;
  float* sY   = S;          // alias, live after conv
  float* R1   = S + 840;
  float* sFE  = S + 1640;   // R1+800
  float* sX4  = S + 1840;
  float* sX4P = S + 2144;

  const float* xb = x + (size_t)b * (LSEQ * DIN);

  // ---- zero the shared row pads ----
  if (lane < CHN) {
    sXEp[lane * 52]     = 0.0f;
    sXEp[lane * 52 + 1] = 0.0f;
  } else if (lane == 16) {
    sXEp[832] = 0.0f;
    sXEp[833] = 0.0f;
  }

  // ---- Phase 1+3: lane l computes xe[l][0..15] (scatter to padded rows) and gi[l][0..17] ----
  if (lane < LSEQ) {
    vf2 xv2[10];
    const float4* xr = (const float4*)(xb + lane * DIN);
    #pragma unroll
    for (int q = 0; q < 5; ++q) {
      float4 v = xr[q];
      vf2 p0; p0.x = v.x; p0.y = v.y;
      vf2 p1; p1.x = v.z; p1.y = v.w;
      xv2[2*q] = p0; xv2[2*q+1] = p1;
    }
    float xe[CHN];
    #pragma unroll
    for (int c = 0; c < CHN; ++c) {
      const vf2* wr = (const vf2*)(we_w + c * DIN);
      vf2 a2; a2.x = we_b[c]; a2.y = 0.0f;
      #pragma unroll
      for (int dp = 0; dp < 10; ++dp) a2 = fma2(xv2[dp], wr[dp], a2);
      xe[c] = a2.x + a2.y;
    }
    // scatter: kk = 16*lane + c ; i = kk/50, m = kk%50 ; addr = 52i + 2 + m
    const int kk0 = lane * CHN;
    const int i0  = kk0 / 50;
    const int m0  = kk0 - i0 * 50;
    float* basep = sXEp + i0 * 52 + 2 + m0;
    #pragma unroll
    for (int c = 0; c < CHN; ++c) {
      const int off = c + ((m0 + c >= 50) ? 2 : 0);
      basep[off] = xe[c];
    }
    vf2 xe2[8];
    #pragma unroll
    for (int p = 0; p < 8; ++p) { xe2[p].x = xe[2*p]; xe2[p].y = xe[2*p+1]; }
    float gi[18];
    #pragma unroll
    for (int g = 0; g < 18; ++g) {
      const vf2* wr = (const vf2*)(wih + g * CHN);
      vf2 a2; a2.x = bih[g]; a2.y = 0.0f;
      #pragma unroll
      for (int p = 0; p < 8; ++p) a2 = fma2(xe2[p], wr[p], a2);
      gi[g] = a2.x + a2.y;
    }
    float4* gd = (float4*)(R1 + lane * 20);
    gd[0] = make_float4(gi[0], gi[1], gi[2], gi[3]);
    gd[1] = make_float4(gi[4], gi[5], gi[6], gi[7]);
    gd[2] = make_float4(gi[8], gi[9], gi[10], gi[11]);
    gd[3] = make_float4(gi[12], gi[13], gi[14], gi[15]);
    *(float2*)(R1 + lane * 20 + 16) = make_float2(gi[16], gi[17]);
  }
  __syncthreads();

  // ---- Phase 4: GRU — wave 0 runs all 4 elements, 16 lanes each (proven R6 form) ----
  if (wave == 0) {
    const int q = lane >> 4;
    const int g = lane & 15;
    const int gb = 16 + (g & 1);
    float wa[HID], wb[HID];
    #pragma unroll
    for (int k = 0; k < HID; ++k) { wa[k] = whh[g * HID + k]; wb[k] = whh[gb * HID + k]; }
    const float ba = bhh[g];
    const float bb = bhh[gb];

    float* giq  = smem + q * SLAB + 840;
    float* x4q  = smem + q * SLAB + 1840;
    float* x4pq = smem + q * SLAB + 2144;

    const int base = q << 4;
    const int srcZ = base + 6 + g;
    const int srcN = base + ((g < 4) ? (12 + g) : (g - 4));

    float hh[HID];
    #pragma unroll
    for (int k = 0; k < HID; ++k) hh[k] = 0.0f;

    for (int l = 0; l < LSEQ; ++l) {
      const float gia = giq[l * 20 + g];
      const float gib = giq[l * 20 + gb];
      float gha = ba, ghb = bb;
      #pragma unroll
      for (int k = 0; k < HID; ++k) {
        gha = fmaf(wa[k], hh[k], gha);
        ghb = fmaf(wb[k], hh[k], ghb);
      }
      const float siga = fsig(gia + gha);
      const float ghx = (g >= 12) ? gha : ghb;
      const float gix = (g >= 12) ? gia : gib;
      const float ghn = __shfl(ghx, srcN);
      const float gin = __shfl(gix, srcN);
      const float z   = __shfl(siga, srcZ);
      const float n   = ftanh(fmaf(siga, ghn, gin));
      const float hn  = fmaf(z, hh[g < HID ? g : 0] - n, n);
      if (g < HID) {
        x4q[l * HID + g] = hn;
        x4pq[l * 8 + g]  = hn;
      }
      #pragma unroll
      for (int k = 0; k < HID; ++k) hh[k] = __shfl(hn, base + k);
    }
  }
  __syncthreads();

  // ---- Phase 2: attn rows (write sAT over dead gi) ----
  if (lane < LSEQ) {
    float a[CHN];
    #pragma unroll
    for (int cc = 0; cc < CHN; ++cc) a[cc] = sXEp[cc * 52 + 2 + lane];  // reshape view
    vf2 a2[8];
    #pragma unroll
    for (int p = 0; p < 8; ++p) { a2[p].x = a[2*p]; a2[p].y = a[2*p+1]; }
    float o[CHN];
    #pragma unroll
    for (int c = 0; c < CHN; ++c) {
      const vf2* wr = (const vf2*)(attn_w + c * CHN);
      vf2 s2; s2.x = attn_b[c]; s2.y = 0.0f;
      #pragma unroll
      for (int p = 0; p < 8; ++p) s2 = fma2(a2[p], wr[p], s2);
      o[c] = ftanh(s2.x + s2.y);
    }
    float4* ad = (float4*)(R1 + lane * CHN);
    ad[0] = make_float4(o[0], o[1], o[2], o[3]);
    ad[1] = make_float4(o[4], o[5], o[6], o[7]);
    ad[2] = make_float4(o[8], o[9], o[10], o[11]);
    ad[3] = make_float4(o[12], o[13], o[14], o[15]);
  }
  __syncthreads();

  // ---- Phase 5: convs (b128 LDS loads, packed-pair taps) fused with attn1 reduction ----
  {
    float* sAT = R1;
    const int o   = lane & 15;
    const int seg = lane >> 4;
    const int s   = seg * 12;
    const int NL  = (seg == 3) ? 14 : 12;
    vf2 Z1[7], Z2[7], Z3[7];
    #pragma unroll
    for (int p = 0; p < 7; ++p) {
      Z1[p] = (vf2)0.0f; Z2[p] = (vf2)0.0f; Z3[p] = (vf2)0.0f;
    }
    for (int i = 0; i < CHN; ++i) {
      const float w1s = c1w[o * CHN + i];
      vf2 W1; W1.x = w1s; W1.y = w1s;
      vf2 W2[3], W3[5];
      #pragma unroll
      for (int t = 0; t < 3; ++t) { float w = c2w[(o * CHN + i) * 3 + t]; W2[t].x = w; W2[t].y = w; }
      #pragma unroll
      for (int t = 0; t < 5; ++t) { float w = c3w[(o * CHN + i) * 5 + t]; W3[t].x = w; W3[t].y = w; }
      const float4* wp = (const float4*)(sXEp + i * 52 + s);
      float4 q0 = wp[0], q1 = wp[1], q2 = wp[2], q3 = wp[3], q4 = wp[4];
      float xv[20] = {q0.x,q0.y,q0.z,q0.w, q1.x,q1.y,q1.z,q1.w,
                      q2.x,q2.y,q2.z,q2.w, q3.x,q3.y,q3.z,q3.w,
                      q4.x,q4.y,q4.z,q4.w};
      vf2 XP[17];
      #pragma unroll
      for (int a = 0; a < 17; ++a) { XP[a].x = xv[a]; XP[a].y = xv[a+1]; }
      #pragma unroll
      for (int p = 0; p < 7; ++p) {
        Z1[p] = fma2(W1, XP[2*p + 2], Z1[p]);
        Z2[p] = fma2(W2[0], XP[2*p + 1], Z2[p]);
        Z2[p] = fma2(W2[1], XP[2*p + 2], Z2[p]);
        Z2[p] = fma2(W2[2], XP[2*p + 3], Z2[p]);
        Z3[p] = fma2(W3[0], XP[2*p    ], Z3[p]);
        Z3[p] = fma2(W3[1], XP[2*p + 1], Z3[p]);
        Z3[p] = fma2(W3[2], XP[2*p + 2], Z3[p]);
        Z3[p] = fma2(W3[3], XP[2*p + 3], Z3[p]);
        Z3[p] = fma2(W3[4], XP[2*p + 4], Z3[p]);
      }
    }
    const float b1v = c1b[o], b2v = c2b[o], b3v = c3b[o];
    float a1 = 0.0f, a2 = 0.0f, a3 = 0.0f;
    #pragma unroll
    for (int u = 0; u < 14; ++u) {
      if (u < NL) {
        int l = s + u;
        float v1 = lrelu(Z1[u >> 1][u & 1] + b1v);
        float v2 = lrelu(Z2[u >> 1][u & 1] + b2v);
        float v3 = lrelu(Z3[u >> 1][u & 1] + b3v);
        int f1 = o * LSEQ + l;
        int f2 = (CHN + o) * LSEQ + l;
        int f3 = (2 * CHN + o) * LSEQ + l;
        a1 += v1 * sAT[(f1 / 48) * CHN + ((f1 % 48) & 15)];
        a2 += v2 * sAT[(f2 / 48) * CHN + ((f2 % 48) & 15)];
        a3 += v3 * sAT[(f3 / 48) * CHN + ((f3 % 48) & 15)];
      }
    }
    a1 += __shfl_xor(a1, 16); a1 += __shfl_xor(a1, 32);
    a2 += __shfl_xor(a2, 16); a2 += __shfl_xor(a2, 32);
    a3 += __shfl_xor(a3, 16); a3 += __shfl_xor(a3, 32);
    if (lane < CHN) { sFE[o] = a1; sFE[CHN + o] = a2; sFE[2 * CHN + o] = a3; }
  }
  __syncthreads();

  // ---- Phase 6a: T rows + column normalizers; sC[j] = {T[0..5], -, WX[8..13]} ----
  float* sC = R1;
  if (lane < LSEQ) {
    float colj[HID];
    #pragma unroll
    for (int h = 0; h < HID; ++h) colj[h] = sX4[h * LSEQ + lane];   // reshape view
    vf2 cj2[3];
    #pragma unroll
    for (int p = 0; p < 3; ++p) { cj2[p].x = colj[2*p]; cj2[p].y = colj[2*p+1]; }
    *(float4*)(sC + lane * 16)     = make_float4(colj[0], colj[1], colj[2], colj[3]);
    *(float2*)(sC + lane * 16 + 4) = make_float2(colj[4], colj[5]);
    float zs = 0.0f;
    for (int i = 0; i < LSEQ; ++i) {
      const float4 r0 = *(const float4*)(sX4P + i * 8);
      const float2 r1 = *(const float2*)(sX4P + i * 8 + 4);
      vf2 p0; p0.x = r0.x; p0.y = r0.y;
      vf2 p1; p1.x = r0.z; p1.y = r0.w;
      vf2 p2; p2.x = r1.x; p2.y = r1.y;
      vf2 s2 = (vf2)0.0f;
      s2 = fma2(p0, cj2[0], s2);
      s2 = fma2(p1, cj2[1], s2);
      s2 = fma2(p2, cj2[2], s2);
      zs += __expf((s2.x + s2.y) * (1.0f / 6.0f));
    }
    const float zi = frcp(zs);
    const float4 q0 = *(const float4*)(sX4P + lane * 8);
    const float2 q1 = *(const float2*)(sX4P + lane * 8 + 4);
    *(float4*)(sC + lane * 16 + 8)  = make_float4(zi*q0.x, zi*q0.y, zi*q0.z, zi*q0.w);
    *(float2*)(sC + lane * 16 + 12) = make_float2(zi*q1.x, zi*q1.y);
  }
  __syncthreads();

  // ---- Phase 6b: y0[i][h] = sum_j exp(s[i,j]/6) * WX[j][h] ----
  if (lane < LSEQ) {
    vf2 ri2[3];
    {
      const float4 q0 = *(const float4*)(sX4P + lane * 8);
      const float2 q1 = *(const float2*)(sX4P + lane * 8 + 4);
      ri2[0].x = q0.x; ri2[0].y = q0.y;
      ri2[1].x = q0.z; ri2[1].y = q0.w;
      ri2[2].x = q1.x; ri2[2].y = q1.y;
    }
    vf2 ya2[3];
    #pragma unroll
    for (int p = 0; p < 3; ++p) ya2[p] = (vf2)0.0f;
    for (int j = 0; j < LSEQ; ++j) {
      const float4 t0 = *(const float4*)(sC + j * 16);
      const float2 t1 = *(const float2*)(sC + j * 16 + 4);
      vf2 p0; p0.x = t0.x; p0.y = t0.y;
      vf2 p1; p1.x = t0.z; p1.y = t0.w;
      vf2 p2; p2.x = t1.x; p2.y = t1.y;
      vf2 s2 = (vf2)0.0f;
      s2 = fma2(ri2[0], p0, s2);
      s2 = fma2(ri2[1], p1, s2);
      s2 = fma2(ri2[2], p2, s2);
      const float e = __expf((s2.x + s2.y) * (1.0f / 6.0f));
      vf2 e2; e2.x = e; e2.y = e;
      const float4 w0 = *(const float4*)(sC + j * 16 + 8);
      const float2 w1 = *(const float2*)(sC + j * 16 + 12);
      vf2 wv0; wv0.x = w0.x; wv0.y = w0.y;
      vf2 wv1; wv1.x = w0.z; wv1.y = w0.w;
      vf2 wv2; wv2.x = w1.x; wv2.y = w1.y;
      ya2[0] = fma2(e2, wv0, ya2[0]);
      ya2[1] = fma2(e2, wv1, ya2[1]);
      ya2[2] = fma2(e2, wv2, ya2[2]);
    }
    *(float2*)(sY + lane * 6)     = make_float2(ya2[0].x, ya2[0].y);
    *(float2*)(sY + lane * 6 + 2) = make_float2(ya2[1].x, ya2[1].y);
    *(float2*)(sY + lane * 6 + 4) = make_float2(ya2[2].x, ya2[2].y);
  }
  __syncthreads();

  // ---- Phase 7: x_gru ----
  if (lane < HID) {
    float s = 0.0f;
    for (int m = 0; m < LSEQ; ++m) s += sY[lane * LSEQ + m];
    sFE[48 + lane] = s;
  }
  __syncthreads();

  // ---- Phase 8: fc ----
  if (lane < 2) {
    float acc = fc3b[lane];
    const float* wr = fc3w + lane * 54;
    #pragma unroll
    for (int k = 0; k < 54; ++k) acc = fmaf(wr[k], sFE[k], acc);
    out[(size_t)b * 2 + lane] = acc;
  }
}

extern "C" void kernel_launch(void* const* d_in, const int* in_sizes, int n_in,
                              void* d_out, int out_size, void* d_ws, size_t ws_size,
                              hipStream_t stream) {
  (void)in_sizes; (void)n_in; (void)d_ws; (void)ws_size; (void)out_size;
  fused_kernel<<<BATCH / 4, 256, 0, stream>>>(
      (const float*)d_in[0],
      (const float*)d_in[1],  (const float*)d_in[2],
      (const float*)d_in[3],  (const float*)d_in[4],
      (const float*)d_in[5],  (const float*)d_in[6],
      (const float*)d_in[7],  (const float*)d_in[8],
      (const float*)d_in[9],  (const float*)d_in[10],
      (const float*)d_in[11], (const float*)d_in[12],
      (const float*)d_in[13], (const float*)d_in[14],
      (const float*)d_in[15], (const float*)d_in[16],
      (float*)d_out);
}